// Round 8
// baseline (171.893 us; speedup 1.0000x reference)
//
#include <hip/hip_runtime.h>

#define NN 4096
#define NE 65536
#define ND 64

// ---------------- K1: per-node dot products + zero x_pooled region of out ----------
__global__ void k1_node_dots(const float* __restrict__ x, const float* __restrict__ wrel,
                             const float* __restrict__ wroot, double* __restrict__ srel,
                             double* __restrict__ sroot, float* __restrict__ out) {
    int gt = blockIdx.x * blockDim.x + threadIdx.x;   // gt in [0, NN*ND)
    out[gt] = 0.0f;                                   // x_pooled base = 0 (replaces memset)
    int node = gt >> 6, lane = gt & 63;
    double xv = (double)x[node * ND + lane];
    double pr = xv * (double)wrel[lane];
    double po = xv * (double)wroot[lane];
    for (int off = 32; off > 0; off >>= 1) {
        pr += __shfl_down(pr, off);
        po += __shfl_down(po, off);
    }
    if (lane == 0) {
        srel[node] = pr;
        sroot[node] = po;
    }
}

// ---------------- K34: CSR + keys + head-poll barrier-free fixpoint ----------------
// earlier(u,v) <=> kq(u) < kq(v), kq = (~mono_f32_score)<<12 | node (stable argsort ties).
// skey[node] u64 = kq<<2 | stat; stat in low 2 bits (0=unresolved,1=center,2=absorbed).
// Blocked rows poll ONE entry (their min-key unresolved in-nbr); rescan only when it
// resolves absorbed. Total rescan work O(E); poll is 1 ds_read_b64 per node per iter.
// LDS: incsr u16 [0,128K). aux 32K: cursor i32 (ph1-4) -> srel f64 (ph5-6) ->
// skey u64 (ph7+). wt ints @ aux+20544 (ph2 / phF, dead for skey at those times).
__global__ void __launch_bounds__(1024) k34_contract(
        const double* __restrict__ srel, const double* __restrict__ sroot,
        const float* __restrict__ bptr, const int* __restrict__ ei,
        int* __restrict__ map_g, int* __restrict__ rem_g, int* __restrict__ relab_g,
        int* __restrict__ perm_a, int* __restrict__ nkeep_g) {
    __shared__ __align__(16) char buf[163840];
    unsigned short* incsr = (unsigned short*)buf;
    char* aux = buf + 131072;
    int* cursor = (int*)aux;
    double* srel_lds = (double*)aux;
    volatile unsigned long long* skey = (volatile unsigned long long*)aux;
    int* wt = (int*)(aux + 20544);
    int tid = threadIdx.x, lane = tid & 63, wv = tid >> 6;

    // ---- Phase 1: in-degree count (LDS atomics) ----
    for (int n = tid; n < NN; n += 1024) cursor[n] = 0;
    __syncthreads();
    const int4* eid4 = (const int4*)(ei + NE);
    for (int i = tid; i < NE / 4; i += 1024) {
        int4 q = eid4[i];
        atomicAdd(&cursor[q.x], 1);
        atomicAdd(&cursor[q.y], 1);
        atomicAdd(&cursor[q.z], 1);
        atomicAdd(&cursor[q.w], 1);
    }
    __syncthreads();

    // ---- Phase 2: exclusive prefix (wave scan); row starts in regs ----
    int t0 = cursor[4 * tid], t1 = cursor[4 * tid + 1];
    int t2 = cursor[4 * tid + 2], t3 = cursor[4 * tid + 3];
    int tot = t0 + t1 + t2 + t3;
    int inc = tot;
    for (int off = 1; off < 64; off <<= 1) {
        int v = __shfl_up(inc, off);
        if (lane >= off) inc += v;
    }
    if (lane == 63) wt[wv] = inc;
    __syncthreads();
    if (wv == 0 && lane < 16) {
        int v = wt[lane];
        for (int off = 1; off < 16; off <<= 1) {
            int u2 = __shfl_up(v, off);
            if (lane >= off) v += u2;
        }
        wt[lane] = v;
    }
    __syncthreads();
    int waveoff = (wv > 0) ? wt[wv - 1] : 0;
    int excl = waveoff + inc - tot;
    int rs4[4], re4[4];
    rs4[0] = excl; rs4[1] = excl + t0; rs4[2] = excl + t0 + t1; rs4[3] = excl + t0 + t1 + t2;
    cursor[4 * tid]     = rs4[0];
    cursor[4 * tid + 1] = rs4[1];
    cursor[4 * tid + 2] = rs4[2];
    cursor[4 * tid + 3] = rs4[3];
    __syncthreads();

    // ---- Phase 3: scatter in-edges (row = dst, entry = src node id) ----
    const int4* eis4 = (const int4*)ei;
    for (int i = tid; i < NE / 4; i += 1024) {
        int4 s = eis4[i];
        int4 d = eid4[i];
        incsr[atomicAdd(&cursor[d.x], 1)] = (unsigned short)s.x;
        incsr[atomicAdd(&cursor[d.y], 1)] = (unsigned short)s.y;
        incsr[atomicAdd(&cursor[d.z], 1)] = (unsigned short)s.z;
        incsr[atomicAdd(&cursor[d.w], 1)] = (unsigned short)s.w;
    }
    __syncthreads();
    for (int t = 0; t < 4; ++t) re4[t] = cursor[4 * tid + t];   // row ends
    __syncthreads();   // cursor region now free

    // ---- Phase 5: stage srel into LDS (aliases cursor region) ----
    {
        double2* sl2 = (double2*)aux;
        const double2* sg2 = (const double2*)srel;
        for (int i = tid; i < NN / 2; i += 1024) sl2[i] = sg2[i];
    }
    __syncthreads();

    // ---- Phase 6: agg row-gather from LDS + key computation (regs only) ----
    double bv = (double)bptr[0];
    unsigned long long base4[4];
    for (int t = 0; t < 4; ++t) {
        int v = 4 * tid + t;
        double s = 0.0;
        for (int e = rs4[t]; e < re4[t]; ++e) s += srel_lds[(int)incsr[e]];
        double arg = s + sroot[v] + bv;
        float sc = tanhf((float)arg);                    // f32 saturation => ref ties
        unsigned m = __float_as_uint(sc);
        m = (m & 0x80000000u) ? ~m : (m | 0x80000000u);  // monotone ascending
        base4[t] = ((unsigned long long)(~m) << 14) | ((unsigned long long)v << 2);
    }
    __syncthreads();   // all srel_lds reads done before skey overwrites the region

    // ---- Phase 7: init skey table ----
    for (int t = 0; t < 4; ++t) skey[4 * tid + t] = base4[t];
    __syncthreads();

    unsigned long long pk4[4], minC4[4], kMin4[4];
    int uMin4[4];
    unsigned resolved = 0, centerm = 0, selfm = 0;

    // rescan row t of node v: compact survivors, recompute minU/uMin, update mC, decide
#define DECIDE(t, v)                                                            \
    if (minC4[t] < kMin4[t]) {                                                  \
        map_g[v] = (int)(minC4[t] & 0xFFFULL);                                  \
        skey[v] = (pk4[t] << 2) | 2ULL;                                         \
        resolved |= 1u << t;                                                    \
    } else if (kMin4[t] == ~0ULL) {                                             \
        map_g[v] = v;                                                           \
        skey[v] = (pk4[t] << 2) | 1ULL;                                         \
        centerm |= 1u << t; resolved |= 1u << t;                                \
    }

#define RESCAN(t, v) {                                                          \
        int lo = rs4[t], hi = re4[t], w = lo;                                   \
        unsigned long long minU = ~0ULL; int um = -1;                           \
        unsigned long long mc = minC4[t];                                       \
        for (int e = lo; e < hi; ++e) {                                         \
            int u = (int)incsr[e];                                              \
            unsigned long long sk = skey[u];                                    \
            int st = (int)(sk & 3ULL);                                          \
            unsigned long long kq = sk >> 2;                                    \
            if (st == 0) { incsr[w++] = (unsigned short)u;                      \
                           if (kq < minU) { minU = kq; um = u; } }              \
            else if (st == 1) { if (kq < mc) mc = kq; }                         \
        }                                                                       \
        re4[t] = w; minC4[t] = mc; kMin4[t] = minU; uMin4[t] = um;              \
        DECIDE(t, v)                                                            \
    }

    // ---- Phase 8 round 0: filter to earlier-only (drop self/later), first decide ----
    for (int t = 0; t < 4; ++t) {
        int v = 4 * tid + t;
        unsigned long long pkv = base4[t] >> 2;
        pk4[t] = pkv;
        minC4[t] = ~0ULL;
        unsigned long long minU = ~0ULL; int um = -1;
        unsigned long long mc = ~0ULL;
        int w = rs4[t];
        for (int e = rs4[t]; e < re4[t]; ++e) {
            int u = (int)incsr[e];
            if (u == v) { selfm |= 1u << t; continue; }
            unsigned long long sk = skey[u];
            unsigned long long kq = sk >> 2;
            if (kq >= pkv) continue;                     // later-position: irrelevant
            int st = (int)(sk & 3ULL);
            if (st == 0) { incsr[w++] = (unsigned short)u;
                           if (kq < minU) { minU = kq; um = u; } }
            else if (st == 1) { if (kq < mc) mc = kq; }
        }
        re4[t] = w; minC4[t] = mc; kMin4[t] = minU; uMin4[t] = um;
        DECIDE(t, v)
    }

    // ---- Phase 8b: head-poll fixpoint (1 ds_read_b64 per blocked node per iter) ----
    int guard = 0;
    while (resolved != 0xFu && guard < 2000000) {
        ++guard;
        for (int t = 0; t < 4; ++t) {
            if (resolved & (1u << t)) continue;
            int v = 4 * tid + t;
            unsigned long long sk = skey[uMin4[t]];
            int st = (int)(sk & 3ULL);
            if (st == 1) {                   // head became center: best possible absorber
                map_g[v] = uMin4[t];
                skey[v] = (pk4[t] << 2) | 2ULL;
                resolved |= 1u << t;
            } else if (st == 2) {            // head absorbed: rescan survivors
                RESCAN(t, v)
            }
        }
    }
    __syncthreads();

    // ---- Phase F: relabel prefix + perm + globals ----
    int remb[4], cnt4 = 0;
    for (int t = 0; t < 4; ++t) {
        remb[t] = ((centerm >> t) & 1) && !((selfm >> t) & 1);
        cnt4 += remb[t];
    }
    int inc2 = cnt4;
    for (int off = 1; off < 64; off <<= 1) {
        int v = __shfl_up(inc2, off);
        if (lane >= off) inc2 += v;
    }
    if (lane == 63) wt[wv] = inc2;
    __syncthreads();
    if (wv == 0 && lane < 16) {
        int v = wt[lane];
        for (int off = 1; off < 16; off <<= 1) {
            int u2 = __shfl_up(v, off);
            if (lane >= off) v += u2;
        }
        wt[lane] = v;
    }
    __syncthreads();
    int woff2 = (wv > 0) ? wt[wv - 1] : 0;
    int run = woff2 + inc2 - cnt4;
    for (int t = 0; t < 4; ++t) {
        int v = 4 * tid + t;
        relab_g[v] = run;
        if (remb[t]) { perm_a[run] = v; ++run; }
        rem_g[v] = remb[t];
    }
    if (tid == 1023) nkeep_g[0] = run;
#undef RESCAN
#undef DECIDE
}

// ---------------- K56: all outputs; x region is pure atomic-add over zeroed base ------
__global__ void k56_outputs(const float* __restrict__ x, const int* __restrict__ map_g,
                            const int* __restrict__ rem_g, const int* __restrict__ relab_g,
                            const int* __restrict__ perm_a, const int* __restrict__ ei,
                            const int* __restrict__ batch, const int* __restrict__ nkeep_g,
                            float* __restrict__ out) {
    int idx = blockIdx.x * blockDim.x + threadIdx.x;
    if (idx < NN * ND) {
        int n = idx >> 6, d = idx & 63;
        int m = map_g[n];                 // m==n for centers & kept free nodes
        if (rem_g[m]) atomicAdd(&out[relab_g[m] * ND + d], x[idx]);
    } else if (idx < NN * ND + 2 * NE) {
        int e = idx - NN * ND;
        int row = e >> 16;                // NE == 1<<16
        int ee = e & (NE - 1);
        int s = ei[ee], t = ei[NE + ee];
        bool valid = (rem_g[s] != 0) && (rem_g[t] != 0);
        int endp = (row == 0) ? s : t;
        out[idx] = valid ? (float)relab_g[endp] : -1.0f;
    } else if (idx < NN * ND + 2 * NE + NN) {
        int r = idx - (NN * ND + 2 * NE);
        int nk = nkeep_g[0];
        out[idx] = (r < nk) ? (float)batch[perm_a[r]] : -1.0f;
    } else if (idx < NN * ND + 2 * NE + 2 * NN) {
        int r = idx - (NN * ND + 2 * NE + NN);
        int nk = nkeep_g[0];
        out[idx] = (r < nk) ? (float)perm_a[r] : -1.0f;
    }
}

extern "C" void kernel_launch(void* const* d_in, const int* in_sizes, int n_in,
                              void* d_out, int out_size, void* d_ws, size_t ws_size,
                              hipStream_t stream) {
    const float* x     = (const float*)d_in[0];
    const int*   ei    = (const int*)d_in[1];
    const int*   batch = (const int*)d_in[2];
    const float* wrel  = (const float*)d_in[3];
    const float* wroot = (const float*)d_in[4];
    const float* b     = (const float*)d_in[5];

    char* ws = (char*)d_ws;
    double* srel  = (double*)(ws + 0);        // 32768
    double* sroot = (double*)(ws + 32768);    // 32768
    int*    map_g = (int*)(ws + 65536);       // 16384
    int*    rem_g = (int*)(ws + 81920);       // 16384
    int*    relab = (int*)(ws + 98304);       // 16384
    int*    perma = (int*)(ws + 114688);      // 16384
    int*    nkeep = (int*)(ws + 131072);      // 64

    float* out = (float*)d_out;

    k1_node_dots<<<NN * ND / 256, 256, 0, stream>>>(x, wrel, wroot, srel, sroot, out);
    k34_contract<<<1, 1024, 0, stream>>>(srel, sroot, b, ei, map_g, rem_g, relab,
                                         perma, nkeep);
    int total_out = NN * ND + 2 * NE + 2 * NN;  // 401408
    k56_outputs<<<(total_out + 255) / 256, 256, 0, stream>>>(x, map_g, rem_g, relab,
                                                             perma, ei, batch, nkeep, out);
}